// Round 2
// baseline (252.483 us; speedup 1.0000x reference)
//
#include <hip/hip_runtime.h>

#define NB 4
#define SEQ 2048
#define NH 16
#define HD 64
#define DMODEL 1024

typedef short bf16x8 __attribute__((ext_vector_type(8)));
typedef float f32x16 __attribute__((ext_vector_type(16)));

union FragU {
    bf16x8 v;
    uint2 u2[2];
    unsigned int w[4];
    unsigned short s[8];
};

// Pack two f32 -> packed bf16 pair (lo in low 16 bits).
#if __has_builtin(__builtin_amdgcn_cvt_pk_bf16_f32)
typedef __bf16 v2bf_t __attribute__((ext_vector_type(2)));
__device__ __forceinline__ unsigned int pack_bf16(float lo, float hi) {
    union { v2bf_t h; unsigned int u; } cv;
    cv.h = __builtin_amdgcn_cvt_pk_bf16_f32(lo, hi);
    return cv.u;
}
#else
__device__ __forceinline__ unsigned int pack_bf16(float lo, float hi) {
    unsigned int a = __float_as_uint(lo) + 0x8000u;
    unsigned int b = __float_as_uint(hi) + 0x8000u;
    return __builtin_amdgcn_perm(b, a, 0x07060302);  // {b.hi16, a.hi16}
}
#endif

#define EXP_SCALE 1.44269504f   // 1/ln2, folded into Q and bias table
#define LN2       0.69314718f   // folded into epilogue store

// Block: 256 threads = 4 waves. Each wave computes a 64q x 64d output tile.
// Per iter: stage K[64][64] (natural) and V[64][64] (transposed) as bf16 in LDS,
// compute X^T = (1.4427*(K*Q^T + bias)) via scaled Q + bias-initialized MFMA
// accumulator (C layout: lane=q col), then p = x * rcp(1+exp2(-x)) (silu*1.4427),
// feed directly as A-operand of P*V; epilogue multiplies by ln2.
__global__ __launch_bounds__(256, 2)
void paa_kernel(const float* __restrict__ Vg, const float* __restrict__ Kg,
                const float* __restrict__ Qg, const float* __restrict__ RW,
                float* __restrict__ Og)
{
    __shared__ __align__(16) unsigned short KsLds[64 * 68];  // [kc][d], stride 68
    __shared__ __align__(16) unsigned short VtLds[64 * 68];  // [d][kc], stride 68
    __shared__ float btab[128];  // 1.4427*bias by distance, clamped at 127

    const int tid  = threadIdx.x;
    const int lane = tid & 63;
    const int wave = tid >> 6;
    const int half = lane >> 5;
    const int l31  = lane & 31;

    const int bid  = blockIdx.x;
    const int bh   = bid & 63;
    const int qt   = bid >> 6;
    const int b    = bh >> 4;
    const int head = bh & 15;

    const int q0w = qt * 256 + wave * 64;

    // ---- bias table (pre-scaled by 1/ln2) ----
    if (tid < 128) {
        int rp = tid;
        int bucket;
        if (rp < 16) bucket = rp;
        else {
            int big = 16 + (int)(logf((float)rp * 0.0625f) * 7.6943736f); // 16/ln(8)
            bucket = big < 31 ? big : 31;
        }
        btab[tid] = RW[bucket * NH + head] * EXP_SCALE;
    }

    // ---- preload Q fragments (B operand of S^T), pre-scaled by 1/ln2 ----
    FragU qf[2][4];
    {
        const float* qbase = Qg + (size_t)(b * SEQ) * DMODEL + head * HD;
        #pragma unroll
        for (int u = 0; u < 2; ++u) {
            const float* qrow = qbase + (size_t)(q0w + u * 32 + l31) * DMODEL;
            #pragma unroll
            for (int kf = 0; kf < 4; ++kf) {
                int dd = kf * 16 + half * 8;
                float4 x0 = *(const float4*)(qrow + dd);
                float4 x1 = *(const float4*)(qrow + dd + 4);
                FragU f;
                f.w[0] = pack_bf16(x0.x * EXP_SCALE, x0.y * EXP_SCALE);
                f.w[1] = pack_bf16(x0.z * EXP_SCALE, x0.w * EXP_SCALE);
                f.w[2] = pack_bf16(x1.x * EXP_SCALE, x1.y * EXP_SCALE);
                f.w[3] = pack_bf16(x1.z * EXP_SCALE, x1.w * EXP_SCALE);
                qf[u][kf] = f;
            }
        }
    }

    f32x16 oacc[2][2];
    #pragma unroll
    for (int u = 0; u < 2; ++u)
        #pragma unroll
        for (int n = 0; n < 2; ++n)
            #pragma unroll
            for (int r = 0; r < 16; ++r) oacc[u][n][r] = 0.0f;

    __syncthreads();
    const float bias_d0  = btab[0];    // all d <= 0  -> bucket 0
    const float bias_far = btab[127];  // all d >= 113 -> bucket 31

    // staging geometry
    const int krow0 = tid >> 4;        // 0..15, +16i
    const int c4    = tid & 15;
    const int kc4   = tid >> 4;        // V: 4 kc rows at kc4*4
    const int d4    = tid & 15;        // V: 4 d cols at d4*4

    const float* kthr = Kg + (size_t)(b * SEQ) * DMODEL + head * HD
                      + (size_t)krow0 * DMODEL + c4 * 4;
    const float* vthr = Vg + (size_t)(b * SEQ) * DMODEL + head * HD
                      + (size_t)(kc4 * 4) * DMODEL + d4 * 4;

    float4 kreg[4], vreg[4];
    // prefetch tile 0
    #pragma unroll
    for (int i = 0; i < 4; ++i) kreg[i] = *(const float4*)(kthr + (size_t)(i * 16) * DMODEL);
    #pragma unroll
    for (int r = 0; r < 4; ++r) vreg[r] = *(const float4*)(vthr + (size_t)r * DMODEL);

    for (int it = 0; it < 32; ++it) {
        const int kcb = it * 64;

        // ---- convert prefetched regs -> LDS (bf16) ----
        #pragma unroll
        for (int i = 0; i < 4; ++i) {
            uint2 w;
            w.x = pack_bf16(kreg[i].x, kreg[i].y);
            w.y = pack_bf16(kreg[i].z, kreg[i].w);
            *(uint2*)&KsLds[(krow0 + i * 16) * 68 + c4 * 4] = w;
        }
        {
            const float* vr = (const float*)vreg;  // vreg[r] component c = vr[r*4+c]
            #pragma unroll
            for (int c = 0; c < 4; ++c) {
                uint2 w;
                w.x = pack_bf16(vr[0 * 4 + c], vr[1 * 4 + c]);
                w.y = pack_bf16(vr[2 * 4 + c], vr[3 * 4 + c]);
                *(uint2*)&VtLds[(d4 * 4 + c) * 68 + kc4 * 4] = w;
            }
        }
        __syncthreads();

        // ---- issue next tile's global loads (latency hidden under compute) ----
        if (it < 31) {
            const float* kn = kthr + (size_t)(kcb + 64) * DMODEL;
            const float* vn = vthr + (size_t)(kcb + 64) * DMODEL;
            #pragma unroll
            for (int i = 0; i < 4; ++i) kreg[i] = *(const float4*)(kn + (size_t)(i * 16) * DMODEL);
            #pragma unroll
            for (int r = 0; r < 4; ++r) vreg[r] = *(const float4*)(vn + (size_t)r * DMODEL);
        }

        // ---- X^T = K * Q^T + bias (bias in accumulator init); then silu -> P ----
        FragU pf[2][4];
        #pragma unroll
        for (int t = 0; t < 2; ++t) {
            const int kcmin = kcb + t * 32;
            // K fragments for this t (shared across u)
            FragU ka[4];
            #pragma unroll
            for (int kf = 0; kf < 4; ++kf) {
                int off = (t * 32 + l31) * 68 + kf * 16 + half * 8;
                ka[kf].u2[0] = *(const uint2*)&KsLds[off];
                ka[kf].u2[1] = *(const uint2*)&KsLds[off + 4];
            }
            f32x16 st[2];
            #pragma unroll
            for (int u = 0; u < 2; ++u) {
                const int qminu = q0w + u * 32;
                if (qminu + 31 - kcmin <= 0) {              // whole tile d<=0
                    #pragma unroll
                    for (int r = 0; r < 16; ++r) st[u][r] = bias_d0;
                } else if (qminu - (kcmin + 31) >= 113) {   // whole tile bucket 31
                    #pragma unroll
                    for (int r = 0; r < 16; ++r) st[u][r] = bias_far;
                } else {                                    // mixed band (~9%)
                    const int dql = qminu + l31 - kcmin - 4 * half;
                    #pragma unroll
                    for (int r = 0; r < 16; ++r) {
                        int dv = dql - ((r & 3) + 8 * (r >> 2));
                        dv = dv < 0 ? 0 : (dv > 127 ? 127 : dv);
                        st[u][r] = btab[dv];
                    }
                }
            }
            #pragma unroll
            for (int kf = 0; kf < 4; ++kf)
                #pragma unroll
                for (int u = 0; u < 2; ++u)
                    st[u] = __builtin_amdgcn_mfma_f32_32x32x16_bf16(
                        ka[kf].v, qf[u][kf].v, st[u], 0, 0, 0);

            // p = x * rcp(1 + exp2(-x))  == 1.4427 * silu(x*ln2)
            #pragma unroll
            for (int u = 0; u < 2; ++u) {
                float vals[16];
                #pragma unroll
                for (int r = 0; r < 16; ++r) {
                    float x = st[u][r];
                    float e = __builtin_amdgcn_exp2f(-x);
                    vals[r] = x * __builtin_amdgcn_rcpf(1.0f + e);
                }
                #pragma unroll
                for (int j = 0; j < 4; ++j)
                    pf[u][t * 2].w[j]     = pack_bf16(vals[2 * j], vals[2 * j + 1]);
                #pragma unroll
                for (int j = 0; j < 4; ++j)
                    pf[u][t * 2 + 1].w[j] = pack_bf16(vals[8 + 2 * j], vals[9 + 2 * j]);
            }
        }

        // ---- O += P * V : V B-fragments address-matched to P's k-slot permutation ----
        #pragma unroll
        for (int f = 0; f < 4; ++f) {
            #pragma unroll
            for (int n = 0; n < 2; ++n) {
                FragU vf;
                int off = (n * 32 + l31) * 68 + f * 16 + half * 4;
                vf.u2[0] = *(const uint2*)&VtLds[off];      // kc offsets 4h..4h+3
                vf.u2[1] = *(const uint2*)&VtLds[off + 8];  // kc offsets 4h+8..4h+11
                #pragma unroll
                for (int u = 0; u < 2; ++u)
                    oacc[u][n] = __builtin_amdgcn_mfma_f32_32x32x16_bf16(
                        pf[u][f].v, vf.v, oacc[u][n], 0, 0, 0);
            }
        }
        __syncthreads();
    }

    // ---- store (x ln2): C layout row=q_local, col=d_local ----
    float* obase = Og + (size_t)(b * SEQ) * DMODEL + head * HD;
    #pragma unroll
    for (int u = 0; u < 2; ++u) {
        #pragma unroll
        for (int r = 0; r < 16; ++r) {
            int q = q0w + u * 32 + (r & 3) + 8 * (r >> 2) + 4 * half;
            float* orow = obase + (size_t)q * DMODEL;
            #pragma unroll
            for (int n = 0; n < 2; ++n)
                orow[n * 32 + l31] = oacc[u][n][r] * LN2;
        }
    }
}

extern "C" void kernel_launch(void* const* d_in, const int* in_sizes, int n_in,
                              void* d_out, int out_size, void* d_ws, size_t ws_size,
                              hipStream_t stream) {
    const float* v  = (const float*)d_in[0];
    const float* k  = (const float*)d_in[1];
    const float* q  = (const float*)d_in[2];
    const float* rw = (const float*)d_in[3];
    float* out = (float*)d_out;
    paa_kernel<<<dim3(512), dim3(256), 0, stream>>>(v, k, q, rw, out);
}

// Round 3
// 220.400 us; speedup vs baseline: 1.1456x; 1.1456x over previous
//
#include <hip/hip_runtime.h>

#define NB 4
#define SEQ 2048
#define NH 16
#define HD 64
#define DMODEL 1024

typedef short bf16x8 __attribute__((ext_vector_type(8)));
typedef float f32x16 __attribute__((ext_vector_type(16)));

union FragU {
    bf16x8 v;
    uint2 u2[2];
    unsigned int w[4];
    unsigned short s[8];
};

// Pack two f32 -> packed bf16 pair (lo in low 16 bits).
#if __has_builtin(__builtin_amdgcn_cvt_pk_bf16_f32)
typedef __bf16 v2bf_t __attribute__((ext_vector_type(2)));
__device__ __forceinline__ unsigned int pack_bf16(float lo, float hi) {
    union { v2bf_t h; unsigned int u; } cv;
    cv.h = __builtin_amdgcn_cvt_pk_bf16_f32(lo, hi);
    return cv.u;
}
#else
__device__ __forceinline__ unsigned int pack_bf16(float lo, float hi) {
    unsigned int a = __float_as_uint(lo) + 0x8000u;
    unsigned int b = __float_as_uint(hi) + 0x8000u;
    return __builtin_amdgcn_perm(b, a, 0x07060302);  // {b.hi16, a.hi16}
}
#endif

#define EXP_SCALE 1.44269504f   // 1/ln2, folded into Q and bias table
#define LN2       0.69314718f   // folded into epilogue store

// Block: 512 threads = 8 waves; each wave computes a 32q x 64d output tile
// (block covers 256 q for one (b,h)). 4 waves/SIMD for latency hiding.
// Per iter: stage K[64][64] (natural) and V[64][64] (transposed) as bf16 in LDS,
// compute X^T = 1.4427*(K*Q^T + bias) via scaled Q + bias-initialized MFMA
// accumulator (C layout: lane=q col), p = x*rcp(1+exp2(-x)), feed directly as
// A-operand of P*V (k-slot permutation matched by V fragment addressing);
// epilogue multiplies by ln2.
__global__ __launch_bounds__(512, 4)
void paa_kernel(const float* __restrict__ Vg, const float* __restrict__ Kg,
                const float* __restrict__ Qg, const float* __restrict__ RW,
                float* __restrict__ Og)
{
    __shared__ __align__(16) unsigned short KsLds[64 * 68];  // [kc][d], stride 68
    __shared__ __align__(16) unsigned short VtLds[64 * 68];  // [d][kc], stride 68
    __shared__ float btab[128];  // 1.4427*bias by distance, clamped at 127

    const int tid  = threadIdx.x;
    const int lane = tid & 63;
    const int wave = tid >> 6;   // 0..7
    const int half = lane >> 5;
    const int l31  = lane & 31;

    const int bid  = blockIdx.x;
    const int bh   = bid & 63;
    const int qt   = bid >> 6;   // 0..7
    const int b    = bh >> 4;
    const int head = bh & 15;

    const int q0w = qt * 256 + wave * 32;   // 32 q rows per wave

    // ---- bias table (pre-scaled by 1/ln2) ----
    if (tid < 128) {
        int rp = tid;
        int bucket;
        if (rp < 16) bucket = rp;
        else {
            int big = 16 + (int)(logf((float)rp * 0.0625f) * 7.6943736f); // 16/ln(8)
            bucket = big < 31 ? big : 31;
        }
        btab[tid] = RW[bucket * NH + head] * EXP_SCALE;
    }

    // ---- preload Q fragments (B operand of S^T), pre-scaled by 1/ln2 ----
    FragU qf[4];
    {
        const float* qrow = Qg + (size_t)(b * SEQ + q0w + l31) * DMODEL + head * HD;
        #pragma unroll
        for (int kf = 0; kf < 4; ++kf) {
            int dd = kf * 16 + half * 8;
            float4 x0 = *(const float4*)(qrow + dd);
            float4 x1 = *(const float4*)(qrow + dd + 4);
            FragU f;
            f.w[0] = pack_bf16(x0.x * EXP_SCALE, x0.y * EXP_SCALE);
            f.w[1] = pack_bf16(x0.z * EXP_SCALE, x0.w * EXP_SCALE);
            f.w[2] = pack_bf16(x1.x * EXP_SCALE, x1.y * EXP_SCALE);
            f.w[3] = pack_bf16(x1.z * EXP_SCALE, x1.w * EXP_SCALE);
            qf[kf] = f;
        }
    }

    f32x16 oacc[2];
    #pragma unroll
    for (int n = 0; n < 2; ++n)
        #pragma unroll
        for (int r = 0; r < 16; ++r) oacc[n][r] = 0.0f;

    __syncthreads();
    const float bias_d0  = btab[0];    // all d <= 0  -> bucket 0
    const float bias_far = btab[127];  // all d >= 113 -> bucket 31

    // staging geometry (512 threads stage a 64x64 tile of K and of V)
    const int krow = tid >> 4;   // 0..31 (+32 for second half)
    const int c4   = tid & 15;
    const int kc2  = tid >> 4;   // V: 2 kc rows at kc2*2
    const int d4   = tid & 15;   // V: 4 d cols at d4*4

    const float* kbase = Kg + (size_t)(b * SEQ) * DMODEL + head * HD;
    const float* vbase = Vg + (size_t)(b * SEQ) * DMODEL + head * HD;

    for (int it = 0; it < 32; ++it) {
        const int kcb = it * 64;

        // ---- stage K: fp32 -> bf16, natural [kc][d] ----
        #pragma unroll
        for (int i = 0; i < 2; ++i) {
            int row = krow + i * 32;
            float4 x = *(const float4*)(kbase + (size_t)(kcb + row) * DMODEL + c4 * 4);
            uint2 w;
            w.x = pack_bf16(x.x, x.y);
            w.y = pack_bf16(x.z, x.w);
            *(uint2*)&KsLds[row * 68 + c4 * 4] = w;
        }
        // ---- stage V transposed: per-thread 2x4 register transpose ----
        {
            const float* vrow = vbase + (size_t)(kcb + kc2 * 2) * DMODEL + d4 * 4;
            float4 x0 = *(const float4*)(vrow);
            float4 x1 = *(const float4*)(vrow + DMODEL);
            *(unsigned int*)&VtLds[(d4 * 4 + 0) * 68 + kc2 * 2] = pack_bf16(x0.x, x1.x);
            *(unsigned int*)&VtLds[(d4 * 4 + 1) * 68 + kc2 * 2] = pack_bf16(x0.y, x1.y);
            *(unsigned int*)&VtLds[(d4 * 4 + 2) * 68 + kc2 * 2] = pack_bf16(x0.z, x1.z);
            *(unsigned int*)&VtLds[(d4 * 4 + 3) * 68 + kc2 * 2] = pack_bf16(x0.w, x1.w);
        }
        __syncthreads();

        // ---- X^T = K * Q^T + bias (bias in accumulator init); silu -> P ----
        FragU pf[4];
        #pragma unroll
        for (int t = 0; t < 2; ++t) {
            const int kcmin = kcb + t * 32;
            FragU ka[4];
            #pragma unroll
            for (int kf = 0; kf < 4; ++kf) {
                int off = (t * 32 + l31) * 68 + kf * 16 + half * 8;
                ka[kf].u2[0] = *(const uint2*)&KsLds[off];
                ka[kf].u2[1] = *(const uint2*)&KsLds[off + 4];
            }
            f32x16 st;
            if (q0w + 31 - kcmin <= 0) {               // whole tile d<=0
                #pragma unroll
                for (int r = 0; r < 16; ++r) st[r] = bias_d0;
            } else if (q0w - (kcmin + 31) >= 113) {    // whole tile bucket 31
                #pragma unroll
                for (int r = 0; r < 16; ++r) st[r] = bias_far;
            } else {                                   // mixed band (~9% of tiles)
                const int dql = q0w + l31 - kcmin - 4 * half;
                #pragma unroll
                for (int r = 0; r < 16; ++r) {
                    int dv = dql - ((r & 3) + 8 * (r >> 2));
                    dv = dv < 0 ? 0 : (dv > 127 ? 127 : dv);
                    st[r] = btab[dv];
                }
            }
            #pragma unroll
            for (int kf = 0; kf < 4; ++kf)
                st = __builtin_amdgcn_mfma_f32_32x32x16_bf16(ka[kf].v, qf[kf].v, st, 0, 0, 0);

            // p = x * rcp(1 + exp2(-x))  == 1.4427 * silu(x*ln2)
            float vals[16];
            #pragma unroll
            for (int r = 0; r < 16; ++r) {
                float x = st[r];
                float e = __builtin_amdgcn_exp2f(-x);
                vals[r] = x * __builtin_amdgcn_rcpf(1.0f + e);
            }
            #pragma unroll
            for (int j = 0; j < 4; ++j)
                pf[t * 2].w[j]     = pack_bf16(vals[2 * j], vals[2 * j + 1]);
            #pragma unroll
            for (int j = 0; j < 4; ++j)
                pf[t * 2 + 1].w[j] = pack_bf16(vals[8 + 2 * j], vals[9 + 2 * j]);
        }

        // ---- O += P * V : V B-fragments address-matched to P's k-slot permutation ----
        #pragma unroll
        for (int f = 0; f < 4; ++f) {
            #pragma unroll
            for (int n = 0; n < 2; ++n) {
                FragU vf;
                int off = (n * 32 + l31) * 68 + f * 16 + half * 4;
                vf.u2[0] = *(const uint2*)&VtLds[off];      // kc offsets 4h..4h+3
                vf.u2[1] = *(const uint2*)&VtLds[off + 8];  // kc offsets 4h+8..4h+11
                oacc[n] = __builtin_amdgcn_mfma_f32_32x32x16_bf16(pf[f].v, vf.v, oacc[n], 0, 0, 0);
            }
        }
        __syncthreads();
    }

    // ---- store (x ln2): C layout row=q_local, col=d_local ----
    float* obase = Og + (size_t)(b * SEQ) * DMODEL + head * HD;
    #pragma unroll
    for (int r = 0; r < 16; ++r) {
        int q = q0w + (r & 3) + 8 * (r >> 2) + 4 * half;
        float* orow = obase + (size_t)q * DMODEL;
        #pragma unroll
        for (int n = 0; n < 2; ++n)
            orow[n * 32 + l31] = oacc[n][r] * LN2;
    }
}

extern "C" void kernel_launch(void* const* d_in, const int* in_sizes, int n_in,
                              void* d_out, int out_size, void* d_ws, size_t ws_size,
                              hipStream_t stream) {
    const float* v  = (const float*)d_in[0];
    const float* k  = (const float*)d_in[1];
    const float* q  = (const float*)d_in[2];
    const float* rw = (const float*)d_in[3];
    float* out = (float*)d_out;
    paa_kernel<<<dim3(512), dim3(512), 0, stream>>>(v, k, q, rw, out);
}